// Round 5
// baseline (45.746 us; speedup 1.0000x reference)
//
#include <hip/hip_runtime.h>

// Problem constants (B,C,D,H,W = 2,64,64,64,64; C8 = 8)
#define B_   2
#define C_   64
#define C8_  8
#define D_   64
#define H_   64
#define W_   64
#define DHW_ (D_ * H_ * W_)        // 262144
#define NROWS (B_ * D_ * H_)       // 8192 attention rows (b,d,h)
#define NELEM (B_ * C_ * DHW_)     // 33554432 floats
#define N4   (NELEM / 4)           // 8388608 float4
#define ROWS_PER_BLK 16
#define ATTN_BLOCKS (NROWS / ROWS_PER_BLK)   // 512

#define COPY_BLOCKS 8192
// chunk = COPY_BLOCKS*256 = 2097152; N4 = 4 * chunk exactly -> single pass,
// 4 independent loads per thread (ILP), then 4 stores.

typedef float fx4 __attribute__((ext_vector_type(4)));

// ---------------------------------------------------------------------------
// Kernel 1: out = x. Single-pass, 4-way ILP float4 copy.
// ---------------------------------------------------------------------------
__global__ __launch_bounds__(256) void copy_x_kernel(
    const fx4* __restrict__ x4, fx4* __restrict__ o4)
{
    const int chunk = COPY_BLOCKS * 256;
    const int i = blockIdx.x * 256 + threadIdx.x;
    fx4 a = x4[i];
    fx4 b = x4[i + chunk];
    fx4 c = x4[i + 2 * chunk];
    fx4 d = x4[i + 3 * chunk];
    o4[i]             = a;
    o4[i + chunk]     = b;
    o4[i + 2 * chunk] = c;
    o4[i + 3 * chunk] = d;
}

// ---------------------------------------------------------------------------
// Kernel 2: self-attention along W per (b,d,h) row; each block handles 16
// rows. Early-exits when gamma == 0 (copy already wrote out = x). When
// gamma != 0, every output element is fully overwritten (g*attn + x).
// ---------------------------------------------------------------------------
__global__ __launch_bounds__(256) void attn3d_row_kernel(
    const float* __restrict__ x,
    const float* __restrict__ Wq, const float* __restrict__ bq,
    const float* __restrict__ Wk, const float* __restrict__ bk,
    const float* __restrict__ Wv, const float* __restrict__ bv,
    const float* __restrict__ gamma,
    float* __restrict__ out)
{
    const float g = gamma[0];
    if (g == 0.0f) return;   // out = g*finite + x = x; copy already wrote it

    const int tid = threadIdx.x;

    __shared__ float Xs[C_][W_ + 1];     // [c][w]
    __shared__ float qs[W_][C8_];        // [w][o]
    __shared__ float ks[W_][C8_];
    __shared__ float vs[W_][C_ + 1];     // [w][c_out]
    __shared__ float as[W_][W_ + 1];     // attention rows

    for (int r = 0; r < ROWS_PER_BLK; ++r) {
        const int bid = blockIdx.x * ROWS_PER_BLK + r;   // row id in [0, NROWS)
        const int b   = bid >> 12;               // / (D_*H_)
        const int dh  = bid & 4095;
        const long long rowbase = (long long)b * C_ * DHW_ + (long long)dh * W_;
        // x[b,c,d,h,w] = x[rowbase + c*DHW_ + w]

        // Stage X row: 64x64 floats, coalesced along w
        for (int e = tid; e < C_ * W_; e += 256) {
            const int c = e >> 6, w = e & 63;
            Xs[c][w] = x[rowbase + (long long)c * DHW_ + w];
        }
        __syncthreads();

        // q, k projections: q[w][o] = sum_c Wq[o][c] * X[c][w] + bq[o]
        for (int e = tid; e < W_ * C8_; e += 256) {
            const int w = e >> 3, o = e & 7;
            float sq = bq[o], sk = bk[o];
            #pragma unroll 8
            for (int c = 0; c < C_; ++c) {
                const float xv = Xs[c][w];
                sq += Wq[o * C_ + c] * xv;
                sk += Wk[o * C_ + c] * xv;
            }
            qs[w][o] = sq;
            ks[w][o] = sk;
        }
        // v projection: v[w][co] = sum_c Wv[co][c] * X[c][w] + bv[co]
        for (int e = tid; e < W_ * C_; e += 256) {
            const int w = e & 63, co = e >> 6;
            float s = bv[co];
            #pragma unroll 8
            for (int c = 0; c < C_; ++c) s += Wv[co * C_ + c] * Xs[c][w];
            vs[w][co] = s;
        }
        __syncthreads();

        // energy + softmax: thread w owns one query row
        if (tid < W_) {
            const int w = tid;
            float e[W_];
            float m = -1e30f;
            for (int wp = 0; wp < W_; ++wp) {
                float s = 0.f;
                #pragma unroll
                for (int o = 0; o < C8_; ++o) s += qs[w][o] * ks[wp][o];
                e[wp] = s;
                m = fmaxf(m, s);
            }
            float sum = 0.f;
            for (int wp = 0; wp < W_; ++wp) {
                const float p = __expf(e[wp] - m);
                e[wp] = p;
                sum += p;
            }
            const float inv = 1.0f / sum;
            for (int wp = 0; wp < W_; ++wp) as[w][wp] = e[wp] * inv;
        }
        __syncthreads();

        // out[w][co] = sum_wp attn[w][wp] * v[wp][co]; write gamma*out + x
        for (int e = tid; e < W_ * C_; e += 256) {
            const int w = e & 63, co = e >> 6;
            float s = 0.f;
            #pragma unroll 8
            for (int wp = 0; wp < W_; ++wp) s += as[w][wp] * vs[wp][co];
            out[rowbase + (long long)co * DHW_ + w] = g * s + Xs[co][w];
        }
        __syncthreads();   // protect LDS reuse across row iterations
    }
}

extern "C" void kernel_launch(void* const* d_in, const int* in_sizes, int n_in,
                              void* d_out, int out_size, void* d_ws, size_t ws_size,
                              hipStream_t stream) {
    const float* x     = (const float*)d_in[0];
    const float* Wq    = (const float*)d_in[1];
    const float* bq    = (const float*)d_in[2];
    const float* Wk    = (const float*)d_in[3];
    const float* bk    = (const float*)d_in[4];
    const float* Wv    = (const float*)d_in[5];
    const float* bv    = (const float*)d_in[6];
    const float* gamma = (const float*)d_in[7];
    float* out = (float*)d_out;

    // 1) out = x — single-pass high-concurrency hand copy
    copy_x_kernel<<<COPY_BLOCKS, 256, 0, stream>>>((const fx4*)x, (fx4*)out);

    // 2) attention overwrite when gamma != 0 (cheap early-exit otherwise)
    attn3d_row_kernel<<<ATTN_BLOCKS, 256, 0, stream>>>(
        x, Wq, bq, Wk, bk, Wv, bv, gamma, out);
}

// Round 6
// 43.454 us; speedup vs baseline: 1.0527x; 1.0527x over previous
//
#include <hip/hip_runtime.h>

// Problem constants (B,C,D,H,W = 2,64,64,64,64; C8 = 8)
#define B_   2
#define C_   64
#define C8_  8
#define D_   64
#define H_   64
#define W_   64
#define DHW_ (D_ * H_ * W_)        // 262144
#define NROWS (B_ * D_ * H_)       // 8192 attention rows (b,d,h)
#define NELEM (B_ * C_ * DHW_)     // 33554432 floats
#define ROWS_PER_BLK 16
#define ATTN_BLOCKS (NROWS / ROWS_PER_BLK)   // 512

// ---------------------------------------------------------------------------
// Self-attention along W per (b,d,h) row; each block handles 16 rows.
// Early-exits when gamma == 0 (then out = x exactly — memcpy already wrote
// it, since gamma * finite_attn + x == x). When gamma != 0, every output
// element is fully overwritten (g*attn + x), so ordering vs. the memcpy is
// irrelevant.
// ---------------------------------------------------------------------------
__global__ __launch_bounds__(256) void attn3d_row_kernel(
    const float* __restrict__ x,
    const float* __restrict__ Wq, const float* __restrict__ bq,
    const float* __restrict__ Wk, const float* __restrict__ bk,
    const float* __restrict__ Wv, const float* __restrict__ bv,
    const float* __restrict__ gamma,
    float* __restrict__ out)
{
    const float g = gamma[0];
    if (g == 0.0f) return;   // out = g*finite + x = x; memcpy already wrote it

    const int tid = threadIdx.x;

    __shared__ float Xs[C_][W_ + 1];     // [c][w]
    __shared__ float qs[W_][C8_];        // [w][o]
    __shared__ float ks[W_][C8_];
    __shared__ float vs[W_][C_ + 1];     // [w][c_out]
    __shared__ float as[W_][W_ + 1];     // attention rows

    for (int r = 0; r < ROWS_PER_BLK; ++r) {
        const int bid = blockIdx.x * ROWS_PER_BLK + r;   // row id in [0, NROWS)
        const int b   = bid >> 12;               // / (D_*H_)
        const int dh  = bid & 4095;
        const long long rowbase = (long long)b * C_ * DHW_ + (long long)dh * W_;
        // x[b,c,d,h,w] = x[rowbase + c*DHW_ + w]

        // Stage X row: 64x64 floats, coalesced along w
        for (int e = tid; e < C_ * W_; e += 256) {
            const int c = e >> 6, w = e & 63;
            Xs[c][w] = x[rowbase + (long long)c * DHW_ + w];
        }
        __syncthreads();

        // q, k projections: q[w][o] = sum_c Wq[o][c] * X[c][w] + bq[o]
        for (int e = tid; e < W_ * C8_; e += 256) {
            const int w = e >> 3, o = e & 7;
            float sq = bq[o], sk = bk[o];
            #pragma unroll 8
            for (int c = 0; c < C_; ++c) {
                const float xv = Xs[c][w];
                sq += Wq[o * C_ + c] * xv;
                sk += Wk[o * C_ + c] * xv;
            }
            qs[w][o] = sq;
            ks[w][o] = sk;
        }
        // v projection: v[w][co] = sum_c Wv[co][c] * X[c][w] + bv[co]
        for (int e = tid; e < W_ * C_; e += 256) {
            const int w = e & 63, co = e >> 6;
            float s = bv[co];
            #pragma unroll 8
            for (int c = 0; c < C_; ++c) s += Wv[co * C_ + c] * Xs[c][w];
            vs[w][co] = s;
        }
        __syncthreads();

        // energy + softmax: thread w owns one query row
        if (tid < W_) {
            const int w = tid;
            float e[W_];
            float m = -1e30f;
            for (int wp = 0; wp < W_; ++wp) {
                float s = 0.f;
                #pragma unroll
                for (int o = 0; o < C8_; ++o) s += qs[w][o] * ks[wp][o];
                e[wp] = s;
                m = fmaxf(m, s);
            }
            float sum = 0.f;
            for (int wp = 0; wp < W_; ++wp) {
                const float p = __expf(e[wp] - m);
                e[wp] = p;
                sum += p;
            }
            const float inv = 1.0f / sum;
            for (int wp = 0; wp < W_; ++wp) as[w][wp] = e[wp] * inv;
        }
        __syncthreads();

        // out[w][co] = sum_wp attn[w][wp] * v[wp][co]; write gamma*out + x
        for (int e = tid; e < W_ * C_; e += 256) {
            const int w = e & 63, co = e >> 6;
            float s = 0.f;
            #pragma unroll 8
            for (int wp = 0; wp < W_; ++wp) s += as[w][wp] * vs[wp][co];
            out[rowbase + (long long)co * DHW_ + w] = g * s + Xs[co][w];
        }
        __syncthreads();   // protect LDS reuse across row iterations
    }
}

extern "C" void kernel_launch(void* const* d_in, const int* in_sizes, int n_in,
                              void* d_out, int out_size, void* d_ws, size_t ws_size,
                              hipStream_t stream) {
    const float* x     = (const float*)d_in[0];
    const float* Wq    = (const float*)d_in[1];
    const float* bq    = (const float*)d_in[2];
    const float* Wk    = (const float*)d_in[3];
    const float* bk    = (const float*)d_in[4];
    const float* Wv    = (const float*)d_in[5];
    const float* bv    = (const float*)d_in[6];
    const float* gamma = (const float*)d_in[7];
    float* out = (float*)d_out;

    // 1) out = x via ROCm's tuned copy blit. Measured 6.3-6.4 TB/s of logical
    //    traffic (262 MB read+write) — at the m13-measured device copy
    //    ceiling; hand kernels (R1 grid-stride, R5 single-pass ILP) were
    //    1.5-2 us slower.
    hipMemcpyAsync(out, x, (size_t)NELEM * sizeof(float),
                   hipMemcpyDeviceToDevice, stream);

    // 2) attention overwrite when gamma != 0 (cheap early-exit otherwise)
    attn3d_row_kernel<<<ATTN_BLOCKS, 256, 0, stream>>>(
        x, Wq, bq, Wk, bk, Wv, bv, gamma, out);
}